// Round 4
// baseline (270.545 us; speedup 1.0000x reference)
//
#include <hip/hip_runtime.h>
#include <hip/hip_bf16.h>
#include <math.h>

typedef __bf16 bf16_t;
typedef bf16_t bf16x4 __attribute__((ext_vector_type(4)));
typedef bf16_t bf16x8 __attribute__((ext_vector_type(8)));
typedef float f32x4 __attribute__((ext_vector_type(4)));

#define T_TOK 8192
#define HDIM  1024
#define IDIM  512
#define NEXP  8
#define NTOT  12
#define MAXROWS (2 * T_TOK + NEXP * 128)   // 17408
#define MAX_MTILES (MAXROWS / 128)         // 136
#define WCAST_BLOCKS 6144                  // (n13+n2)/256 exactly

// ---------------- async global->LDS, 16B per lane ----------------
__device__ __forceinline__ void gll16(const bf16_t* g, bf16_t* l) {
  __builtin_amdgcn_global_load_lds((__attribute__((address_space(1))) void*)g,
                                   (__attribute__((address_space(3))) void*)l,
                                   16, 0, 0);
}

// ======== merged: weight casts + sel zero-init + router (+x->bf16 cast) ========
// Both roles are BW-bound and independent -> co-scheduling overlaps their traffic.
__global__ __launch_bounds__(256) void pre_kernel(
    const float* __restrict__ w13, const float* __restrict__ w2,
    const float* __restrict__ x, const float* __restrict__ rw,
    const float* __restrict__ bias,
    bf16_t* __restrict__ w13b, bf16_t* __restrict__ w2b, bf16_t* __restrict__ xb,
    int* __restrict__ tk_e, float* __restrict__ tk_w, float* __restrict__ zscale,
    int* __restrict__ sel_tok, float* __restrict__ sel_w) {
  const int bid = blockIdx.x;
  const int tid = threadIdx.x;
  if (bid < WCAST_BLOCKS) {
    size_t gid = (size_t)bid * 256 + tid;
    if (gid < MAXROWS) { sel_tok[gid] = 0; sel_w[gid] = 0.f; }
    const size_t n13 = (size_t)NEXP * 2 * IDIM * HDIM / 8;  // 1048576
    const float* in; bf16_t* outp; size_t i;
    if (gid < n13) { in = w13; outp = w13b; i = gid * 8; }
    else           { in = w2;  outp = w2b;  i = (gid - n13) * 8; }
    float4 a = *(const float4*)&in[i];
    float4 b = *(const float4*)&in[i + 4];
    bf16x8 o;
    o[0] = (bf16_t)a.x; o[1] = (bf16_t)a.y; o[2] = (bf16_t)a.z; o[3] = (bf16_t)a.w;
    o[4] = (bf16_t)b.x; o[5] = (bf16_t)b.y; o[6] = (bf16_t)b.z; o[7] = (bf16_t)b.w;
    *(bf16x8*)&outp[i] = o;
    return;
  }
  // router role: 4 waves = 4 tokens per block
  int t = (bid - WCAST_BLOCKS) * 4 + (tid >> 6);
  int l = tid & 63;
  const float4* xr = (const float4*)(x + (size_t)t * HDIM);
  float4 xv[4];
#pragma unroll
  for (int i = 0; i < 4; i++) xv[i] = xr[l + 64 * i];
#pragma unroll
  for (int i = 0; i < 4; i++) {
    bf16x4 o;
    o[0] = (bf16_t)xv[i].x; o[1] = (bf16_t)xv[i].y;
    o[2] = (bf16_t)xv[i].z; o[3] = (bf16_t)xv[i].w;
    *(bf16x4*)&xb[(size_t)t * HDIM + (size_t)(l + 64 * i) * 4] = o;
  }
  float part[NTOT];
#pragma unroll
  for (int e = 0; e < NTOT; e++) {
    const float4* wr = (const float4*)(rw + (size_t)e * HDIM);
    float s = 0.f;
#pragma unroll
    for (int i = 0; i < 4; i++) {
      float4 w = wr[l + 64 * i];
      s += xv[i].x * w.x + xv[i].y * w.y + xv[i].z * w.z + xv[i].w * w.w;
    }
    part[e] = s;
  }
#pragma unroll
  for (int off = 32; off > 0; off >>= 1)
#pragma unroll
    for (int e = 0; e < NTOT; e++) part[e] += __shfl_down(part[e], off);

  if (l == 0) {
    float mx = part[0];
#pragma unroll
    for (int e = 1; e < NTOT; e++) mx = fmaxf(mx, part[e]);
    float p[NTOT], den = 0.f;
#pragma unroll
    for (int e = 0; e < NTOT; e++) { p[e] = expf(part[e] - mx); den += p[e]; }
    float inv = 1.f / den;
#pragma unroll
    for (int e = 0; e < NTOT; e++) p[e] *= inv;
    float s0 = -1e30f, s1 = -1e30f; int i0 = 0, i1 = 0;
#pragma unroll
    for (int e = 0; e < NTOT; e++) {
      float v = p[e] + bias[e];
      if (v > s0) { s1 = s0; i1 = i0; s0 = v; i0 = e; }
      else if (v > s1) { s1 = v; i1 = e; }
    }
    float zs = 0.f;
    int idx[2] = { i0, i1 };
#pragma unroll
    for (int k = 0; k < 2; k++) {
      int e = idx[k];
      float w = p[e];
      if (e >= NEXP) { zs += w; tk_e[2 * t + k] = -1; tk_w[2 * t + k] = 0.f; }
      else           { tk_e[2 * t + k] = e; tk_w[2 * t + k] = w; }
    }
    zscale[t] = zs;
  }
}

// ---------------- fused count + scan (single block) ----------------
__global__ void countscan_kernel(const int* __restrict__ tk_e, int* __restrict__ cursor,
                                 int* __restrict__ total_rows, int* __restrict__ tile_e,
                                 int* __restrict__ tile_p0, int* __restrict__ n_mtiles) {
  __shared__ int lc[NEXP];
  int tid = threadIdx.x;
  if (tid < NEXP) lc[tid] = 0;
  __syncthreads();
  int cnt[NEXP];
#pragma unroll
  for (int j = 0; j < NEXP; j++) cnt[j] = 0;
  for (int i = tid; i < 2 * T_TOK; i += 256) {
    int e = tk_e[i];
#pragma unroll
    for (int j = 0; j < NEXP; j++) cnt[j] += (e == j) ? 1 : 0;
  }
#pragma unroll
  for (int off = 32; off > 0; off >>= 1)
#pragma unroll
    for (int j = 0; j < NEXP; j++) cnt[j] += __shfl_down(cnt[j], off);
  if ((tid & 63) == 0)
#pragma unroll
    for (int j = 0; j < NEXP; j++) atomicAdd(&lc[j], cnt[j]);
  __syncthreads();
  if (tid == 0) {
    int run = 0, nt = 0;
    for (int e = 0; e < NEXP; e++) {
      cursor[e] = run;
      int ntile = (lc[e] + 127) / 128;
      for (int i = 0; i < ntile; i++) {
        tile_e[nt] = e;
        tile_p0[nt] = run + i * 128;
        nt++;
      }
      run += ntile * 128;
    }
    *total_rows = run;
    *n_mtiles = nt;
  }
}

// ---------------- assign (writes pos for combine) ----------------
__global__ void assign_kernel(const int* __restrict__ tk_e, const float* __restrict__ tk_w,
                              int* __restrict__ cursor, int* __restrict__ sel_tok,
                              float* __restrict__ sel_w, int* __restrict__ pos) {
  __shared__ int lc[NEXP];
  __shared__ int lbase[NEXP];
  int tid = threadIdx.x;
  if (tid < NEXP) lc[tid] = 0;
  __syncthreads();
  int t = blockIdx.x * blockDim.x + tid;
  int e0 = tk_e[2 * t], e1 = tk_e[2 * t + 1];
  int r0 = (e0 >= 0) ? atomicAdd(&lc[e0], 1) : -1;
  int r1 = (e1 >= 0) ? atomicAdd(&lc[e1], 1) : -1;
  __syncthreads();
  if (tid < NEXP) lbase[tid] = atomicAdd(&cursor[tid], lc[tid]);
  __syncthreads();
  int p0 = -1, p1 = -1;
  if (e0 >= 0) { p0 = lbase[e0] + r0; sel_tok[p0] = t; sel_w[p0] = 2.5f * tk_w[2 * t]; }
  if (e1 >= 0) { p1 = lbase[e1] + r1; sel_tok[p1] = t; sel_w[p1] = 2.5f * tk_w[2 * t + 1]; }
  pos[2 * t] = p0;
  pos[2 * t + 1] = p1;
}

// ======== GEMM1+SiLU: 128x256 block, 4x8 frags, XCD-chunked block mapping ========
// 1-D grid 544 (=8*68). L=(b&7)*68+(b>>3): XCD k owns contiguous L-chunk -> one
// (y, ti-range) -> its 512KB B-panel stays L2-resident (T1). Swizzled LDS as before.
__global__ __launch_bounds__(256, 2) void gemm1_kernel(
    const bf16_t* __restrict__ xb, const bf16_t* __restrict__ w13b,
    const int* __restrict__ sel_tok, const int* __restrict__ tile_e,
    const int* __restrict__ tile_p0, const int* __restrict__ n_mtiles,
    bf16_t* __restrict__ actb) {
  const int b = blockIdx.x;                   // 544 blocks
  const int L = (b & 7) * 68 + (b >> 3);      // XCD-contiguous chunks of 68
  const int ti = L % MAX_MTILES;
  const int g0 = (L / MAX_MTILES) * 128;      // gate-col base
  if (ti >= *n_mtiles) return;
  const int e = tile_e[ti];
  const int p0 = tile_p0[ti];

  __shared__ alignas(16) bf16_t As[128 * 64];
  __shared__ alignas(16) bf16_t Bs[256 * 64];
  const int tid = threadIdx.x;
  const int w = tid >> 6, l = tid & 63;
  const int wr = w >> 1, wc = w & 1;
  const int quad = l >> 4, c16 = l & 15;

  const int srow = tid >> 3;
  const int csrc = ((tid & 7) ^ (srow & 7)) * 8;
  const bf16_t* w13e = w13b + (size_t)e * (2 * IDIM) * HDIM;
  const bf16_t* Asrc[4];
  const bf16_t* Bsrc[8];
#pragma unroll
  for (int s = 0; s < 4; s++) {
    int tok = sel_tok[p0 + s * 32 + srow];
    Asrc[s] = xb + (size_t)tok * HDIM + csrc;
  }
#pragma unroll
  for (int s = 0; s < 8; s++) {
    int col = g0 + (s >> 1) * 32 + srow + ((s & 1) ? IDIM : 0);
    Bsrc[s] = w13e + (size_t)col * HDIM + csrc;
  }

  f32x4 acc[4][8];
#pragma unroll
  for (int i = 0; i < 4; i++)
#pragma unroll
    for (int j = 0; j < 8; j++) acc[i][j] = (f32x4){0.f, 0.f, 0.f, 0.f};

  for (int k0 = 0; k0 < HDIM; k0 += 64) {
#pragma unroll
    for (int s = 0; s < 4; s++) gll16(Asrc[s] + k0, &As[s * 2048 + w * 512]);
#pragma unroll
    for (int s = 0; s < 8; s++) gll16(Bsrc[s] + k0, &Bs[s * 2048 + w * 512]);
    __syncthreads();
#pragma unroll
    for (int kk = 0; kk < 2; kk++) {
      const int kch = ((kk * 4 + quad) ^ (c16 & 7)) * 8;
      bf16x8 af[4], bfv[8];
#pragma unroll
      for (int mt = 0; mt < 4; mt++)
        af[mt] = *(const bf16x8*)&As[(wr * 64 + mt * 16 + c16) * 64 + kch];
#pragma unroll
      for (int nt = 0; nt < 8; nt++)
        bfv[nt] = *(const bf16x8*)&Bs[(wc * 128 + nt * 16 + c16) * 64 + kch];
#pragma unroll
      for (int mt = 0; mt < 4; mt++)
#pragma unroll
        for (int nt = 0; nt < 8; nt++)
          acc[mt][nt] = __builtin_amdgcn_mfma_f32_16x16x32_bf16(af[mt], bfv[nt], acc[mt][nt], 0, 0, 0);
    }
    __syncthreads();
  }

#pragma unroll
  for (int mt = 0; mt < 4; mt++) {
    int rowb = p0 + wr * 64 + mt * 16 + quad * 4;
#pragma unroll
    for (int ntg = 0; ntg < 4; ntg++) {
      int nt = (ntg & 1) + (ntg >> 1) * 4;           // 0,1,4,5 = gate; nt+2 = up
      int col = g0 + (wc * 2 + (nt >> 2)) * 32 + (nt & 1) * 16 + c16;
#pragma unroll
      for (int r = 0; r < 4; r++) {
        float g = acc[mt][nt][r];
        float u = acc[mt][nt + 2][r];
        float s = g / (1.f + expf(-g));
        actb[(size_t)(rowb + r) * IDIM + col] = (bf16_t)(s * u);
      }
    }
  }
}

// ======== GEMM2: 128x256 block, 4x8 frags, XCD-chunked, writes eob (cw-scaled) ========
__global__ __launch_bounds__(256, 2) void gemm2_kernel(
    const bf16_t* __restrict__ actb, const bf16_t* __restrict__ w2b,
    const float* __restrict__ sel_w, const int* __restrict__ tile_e,
    const int* __restrict__ tile_p0, const int* __restrict__ n_mtiles,
    bf16_t* __restrict__ eob) {
  const int b = blockIdx.x;                   // 544 blocks
  const int L = (b & 7) * 68 + (b >> 3);
  const int ti = L % MAX_MTILES;
  const int n0 = (L / MAX_MTILES) * 256;
  if (ti >= *n_mtiles) return;
  const int e = tile_e[ti];
  const int p0 = tile_p0[ti];

  __shared__ alignas(16) bf16_t As[128 * 64];
  __shared__ alignas(16) bf16_t Bs[256 * 64];
  const int tid = threadIdx.x;
  const int w = tid >> 6, l = tid & 63;
  const int wr = w >> 1, wc = w & 1;
  const int quad = l >> 4, c16 = l & 15;

  const int srow = tid >> 3;
  const int csrc = ((tid & 7) ^ (srow & 7)) * 8;
  const bf16_t* w2e = w2b + (size_t)e * HDIM * IDIM;
  const bf16_t* Asrc[4];
  const bf16_t* Bsrc[8];
#pragma unroll
  for (int s = 0; s < 4; s++)
    Asrc[s] = actb + (size_t)(p0 + s * 32 + srow) * IDIM + csrc;
#pragma unroll
  for (int s = 0; s < 8; s++)
    Bsrc[s] = w2e + (size_t)(n0 + s * 32 + srow) * IDIM + csrc;

  f32x4 acc[4][8];
#pragma unroll
  for (int i = 0; i < 4; i++)
#pragma unroll
    for (int j = 0; j < 8; j++) acc[i][j] = (f32x4){0.f, 0.f, 0.f, 0.f};

  for (int k0 = 0; k0 < IDIM; k0 += 64) {
#pragma unroll
    for (int s = 0; s < 4; s++) gll16(Asrc[s] + k0, &As[s * 2048 + w * 512]);
#pragma unroll
    for (int s = 0; s < 8; s++) gll16(Bsrc[s] + k0, &Bs[s * 2048 + w * 512]);
    __syncthreads();
#pragma unroll
    for (int kk = 0; kk < 2; kk++) {
      const int kch = ((kk * 4 + quad) ^ (c16 & 7)) * 8;
      bf16x8 af[4], bfv[8];
#pragma unroll
      for (int mt = 0; mt < 4; mt++)
        af[mt] = *(const bf16x8*)&As[(wr * 64 + mt * 16 + c16) * 64 + kch];
#pragma unroll
      for (int nt = 0; nt < 8; nt++)
        bfv[nt] = *(const bf16x8*)&Bs[(wc * 128 + nt * 16 + c16) * 64 + kch];
#pragma unroll
      for (int mt = 0; mt < 4; mt++)
#pragma unroll
        for (int nt = 0; nt < 8; nt++)
          acc[mt][nt] = __builtin_amdgcn_mfma_f32_16x16x32_bf16(af[mt], bfv[nt], acc[mt][nt], 0, 0, 0);
    }
    __syncthreads();
  }

#pragma unroll
  for (int mt = 0; mt < 4; mt++) {
    int rowb = wr * 64 + mt * 16 + quad * 4;
    float cw[4];
#pragma unroll
    for (int r = 0; r < 4; r++) cw[r] = sel_w[p0 + rowb + r];
#pragma unroll
    for (int nt = 0; nt < 8; nt++) {
      int col = n0 + wc * 128 + nt * 16 + c16;
#pragma unroll
      for (int r = 0; r < 4; r++)
        eob[(size_t)(p0 + rowb + r) * HDIM + col] = (bf16_t)(cw[r] * acc[mt][nt][r]);
    }
  }
}

// ---------------- final combine ----------------
__global__ void combine_kernel(const float* __restrict__ x, const float* __restrict__ zscale,
                               const int* __restrict__ pos, const bf16_t* __restrict__ eob,
                               float* __restrict__ out) {
  size_t gid = (size_t)blockIdx.x * blockDim.x + threadIdx.x;
  size_t t = gid >> 7;
  size_t j = (gid & 127) << 3;
  float zs = zscale[t];
  int p0 = pos[2 * t], p1 = pos[2 * t + 1];
  float4 a = *(const float4*)&x[t * HDIM + j];
  float4 b = *(const float4*)&x[t * HDIM + j + 4];
  float o[8] = { zs * a.x, zs * a.y, zs * a.z, zs * a.w,
                 zs * b.x, zs * b.y, zs * b.z, zs * b.w };
  if (p0 >= 0) {
    bf16x8 v = *(const bf16x8*)&eob[(size_t)p0 * HDIM + j];
#pragma unroll
    for (int k = 0; k < 8; k++) o[k] += (float)v[k];
  }
  if (p1 >= 0) {
    bf16x8 v = *(const bf16x8*)&eob[(size_t)p1 * HDIM + j];
#pragma unroll
    for (int k = 0; k < 8; k++) o[k] += (float)v[k];
  }
  *(float4*)&out[t * HDIM + j] = make_float4(o[0], o[1], o[2], o[3]);
  *(float4*)&out[t * HDIM + j + 4] = make_float4(o[4], o[5], o[6], o[7]);
}

extern "C" void kernel_launch(void* const* d_in, const int* in_sizes, int n_in,
                              void* d_out, int out_size, void* d_ws, size_t ws_size,
                              hipStream_t stream) {
  const float* x    = (const float*)d_in[0];
  const float* rw   = (const float*)d_in[1];
  const float* bias = (const float*)d_in[2];
  const float* w13  = (const float*)d_in[3];
  const float* w2   = (const float*)d_in[4];
  float* out = (float*)d_out;

  char* ws = (char*)d_ws;
  bf16_t* w13b = (bf16_t*)ws;  ws += (size_t)NEXP * 2 * IDIM * HDIM * 2;
  bf16_t* w2b  = (bf16_t*)ws;  ws += (size_t)NEXP * HDIM * IDIM * 2;
  bf16_t* xb   = (bf16_t*)ws;  ws += (size_t)T_TOK * HDIM * 2;
  bf16_t* actb = (bf16_t*)ws;  ws += (size_t)MAXROWS * IDIM * 2;
  bf16_t* eob  = (bf16_t*)ws;  ws += (size_t)MAXROWS * HDIM * 2;
  int*   tk_e    = (int*)ws;   ws += (size_t)T_TOK * 2 * 4;
  float* tk_w    = (float*)ws; ws += (size_t)T_TOK * 2 * 4;
  float* zscale  = (float*)ws; ws += (size_t)T_TOK * 4;
  int*   pos     = (int*)ws;   ws += (size_t)T_TOK * 2 * 4;
  int*   sel_tok = (int*)ws;   ws += (size_t)MAXROWS * 4;
  float* sel_w   = (float*)ws; ws += (size_t)MAXROWS * 4;
  int*   cursor  = (int*)ws;   ws += NEXP * 4;
  int*   total_rows = (int*)ws; ws += 4;
  int*   tile_e  = (int*)ws;   ws += MAX_MTILES * 4;
  int*   tile_p0 = (int*)ws;   ws += MAX_MTILES * 4;
  int*   n_mtiles = (int*)ws;  ws += 4;

  // merged: weight casts + zero-init + router (+x->bf16)
  pre_kernel<<<WCAST_BLOCKS + T_TOK / 4, 256, 0, stream>>>(
      w13, w2, x, rw, bias, w13b, w2b, xb, tk_e, tk_w, zscale, sel_tok, sel_w);
  countscan_kernel<<<1, 256, 0, stream>>>(tk_e, cursor, total_rows,
                                          tile_e, tile_p0, n_mtiles);
  assign_kernel<<<T_TOK / 256, 256, 0, stream>>>(tk_e, tk_w, cursor, sel_tok, sel_w, pos);

  // GEMM1 + SiLU: 1-D grid, XCD-chunked (8*68 = 544)
  gemm1_kernel<<<MAX_MTILES * ((2 * IDIM) / 256), 256, 0, stream>>>(
      xb, w13b, sel_tok, tile_e, tile_p0, n_mtiles, actb);
  // GEMM2: 1-D grid, XCD-chunked; writes eob
  gemm2_kernel<<<MAX_MTILES * (HDIM / 256), 256, 0, stream>>>(
      actb, w2b, sel_w, tile_e, tile_p0, n_mtiles, eob);

  combine_kernel<<<(size_t)T_TOK * HDIM / 8 / 256, 256, 0, stream>>>(
      x, zscale, pos, eob, out);
}

// Round 5
// 236.033 us; speedup vs baseline: 1.1462x; 1.1462x over previous
//
#include <hip/hip_runtime.h>
#include <hip/hip_bf16.h>
#include <math.h>

typedef __bf16 bf16_t;
typedef bf16_t bf16x4 __attribute__((ext_vector_type(4)));
typedef bf16_t bf16x8 __attribute__((ext_vector_type(8)));
typedef float f32x4 __attribute__((ext_vector_type(4)));

#define T_TOK 8192
#define HDIM  1024
#define IDIM  512
#define NEXP  8
#define NTOT  12
#define MAXROWS (2 * T_TOK + NEXP * 128)   // 17408
#define MAX_MTILES (MAXROWS / 128)         // 136
#define WCAST_BLOCKS 6144                  // (n13+n2)/256 exactly

// ---------------- async global->LDS, 16B per lane ----------------
__device__ __forceinline__ void gll16(const bf16_t* g, bf16_t* l) {
  __builtin_amdgcn_global_load_lds((__attribute__((address_space(1))) void*)g,
                                   (__attribute__((address_space(3))) void*)l,
                                   16, 0, 0);
}

// ======== merged: weight casts + sel zero-init + router (+x->bf16 cast) ========
__global__ __launch_bounds__(256) void pre_kernel(
    const float* __restrict__ w13, const float* __restrict__ w2,
    const float* __restrict__ x, const float* __restrict__ rw,
    const float* __restrict__ bias,
    bf16_t* __restrict__ w13b, bf16_t* __restrict__ w2b, bf16_t* __restrict__ xb,
    int* __restrict__ tk_e, float* __restrict__ tk_w, float* __restrict__ zscale,
    int* __restrict__ sel_tok, float* __restrict__ sel_w) {
  const int bid = blockIdx.x;
  const int tid = threadIdx.x;
  if (bid < WCAST_BLOCKS) {
    size_t gid = (size_t)bid * 256 + tid;
    if (gid < MAXROWS) { sel_tok[gid] = 0; sel_w[gid] = 0.f; }
    const size_t n13 = (size_t)NEXP * 2 * IDIM * HDIM / 8;  // 1048576
    const float* in; bf16_t* outp; size_t i;
    if (gid < n13) { in = w13; outp = w13b; i = gid * 8; }
    else           { in = w2;  outp = w2b;  i = (gid - n13) * 8; }
    float4 a = *(const float4*)&in[i];
    float4 b = *(const float4*)&in[i + 4];
    bf16x8 o;
    o[0] = (bf16_t)a.x; o[1] = (bf16_t)a.y; o[2] = (bf16_t)a.z; o[3] = (bf16_t)a.w;
    o[4] = (bf16_t)b.x; o[5] = (bf16_t)b.y; o[6] = (bf16_t)b.z; o[7] = (bf16_t)b.w;
    *(bf16x8*)&outp[i] = o;
    return;
  }
  // router role: 4 waves = 4 tokens per block
  int t = (bid - WCAST_BLOCKS) * 4 + (tid >> 6);
  int l = tid & 63;
  const float4* xr = (const float4*)(x + (size_t)t * HDIM);
  float4 xv[4];
#pragma unroll
  for (int i = 0; i < 4; i++) xv[i] = xr[l + 64 * i];
#pragma unroll
  for (int i = 0; i < 4; i++) {
    bf16x4 o;
    o[0] = (bf16_t)xv[i].x; o[1] = (bf16_t)xv[i].y;
    o[2] = (bf16_t)xv[i].z; o[3] = (bf16_t)xv[i].w;
    *(bf16x4*)&xb[(size_t)t * HDIM + (size_t)(l + 64 * i) * 4] = o;
  }
  float part[NTOT];
#pragma unroll
  for (int e = 0; e < NTOT; e++) {
    const float4* wr = (const float4*)(rw + (size_t)e * HDIM);
    float s = 0.f;
#pragma unroll
    for (int i = 0; i < 4; i++) {
      float4 w = wr[l + 64 * i];
      s += xv[i].x * w.x + xv[i].y * w.y + xv[i].z * w.z + xv[i].w * w.w;
    }
    part[e] = s;
  }
#pragma unroll
  for (int off = 32; off > 0; off >>= 1)
#pragma unroll
    for (int e = 0; e < NTOT; e++) part[e] += __shfl_down(part[e], off);

  if (l == 0) {
    float mx = part[0];
#pragma unroll
    for (int e = 1; e < NTOT; e++) mx = fmaxf(mx, part[e]);
    float p[NTOT], den = 0.f;
#pragma unroll
    for (int e = 0; e < NTOT; e++) { p[e] = expf(part[e] - mx); den += p[e]; }
    float inv = 1.f / den;
#pragma unroll
    for (int e = 0; e < NTOT; e++) p[e] *= inv;
    float s0 = -1e30f, s1 = -1e30f; int i0 = 0, i1 = 0;
#pragma unroll
    for (int e = 0; e < NTOT; e++) {
      float v = p[e] + bias[e];
      if (v > s0) { s1 = s0; i1 = i0; s0 = v; i0 = e; }
      else if (v > s1) { s1 = v; i1 = e; }
    }
    float zs = 0.f;
    int idx[2] = { i0, i1 };
#pragma unroll
    for (int k = 0; k < 2; k++) {
      int e = idx[k];
      float w = p[e];
      if (e >= NEXP) { zs += w; tk_e[2 * t + k] = -1; tk_w[2 * t + k] = 0.f; }
      else           { tk_e[2 * t + k] = e; tk_w[2 * t + k] = w; }
    }
    zscale[t] = zs;
  }
}

// ---------------- fused count + scan (single block) ----------------
__global__ void countscan_kernel(const int* __restrict__ tk_e, int* __restrict__ cursor,
                                 int* __restrict__ total_rows, int* __restrict__ tile_e,
                                 int* __restrict__ tile_p0, int* __restrict__ n_mtiles) {
  __shared__ int lc[NEXP];
  int tid = threadIdx.x;
  if (tid < NEXP) lc[tid] = 0;
  __syncthreads();
  int cnt[NEXP];
#pragma unroll
  for (int j = 0; j < NEXP; j++) cnt[j] = 0;
  for (int i = tid; i < 2 * T_TOK; i += 256) {
    int e = tk_e[i];
#pragma unroll
    for (int j = 0; j < NEXP; j++) cnt[j] += (e == j) ? 1 : 0;
  }
#pragma unroll
  for (int off = 32; off > 0; off >>= 1)
#pragma unroll
    for (int j = 0; j < NEXP; j++) cnt[j] += __shfl_down(cnt[j], off);
  if ((tid & 63) == 0)
#pragma unroll
    for (int j = 0; j < NEXP; j++) atomicAdd(&lc[j], cnt[j]);
  __syncthreads();
  if (tid == 0) {
    int run = 0, nt = 0;
    for (int e = 0; e < NEXP; e++) {
      cursor[e] = run;
      int ntile = (lc[e] + 127) / 128;
      for (int i = 0; i < ntile; i++) {
        tile_e[nt] = e;
        tile_p0[nt] = run + i * 128;
        nt++;
      }
      run += ntile * 128;
    }
    *total_rows = run;
    *n_mtiles = nt;
  }
}

// ---------------- assign (writes pos for combine) ----------------
__global__ void assign_kernel(const int* __restrict__ tk_e, const float* __restrict__ tk_w,
                              int* __restrict__ cursor, int* __restrict__ sel_tok,
                              float* __restrict__ sel_w, int* __restrict__ pos) {
  __shared__ int lc[NEXP];
  __shared__ int lbase[NEXP];
  int tid = threadIdx.x;
  if (tid < NEXP) lc[tid] = 0;
  __syncthreads();
  int t = blockIdx.x * blockDim.x + tid;
  int e0 = tk_e[2 * t], e1 = tk_e[2 * t + 1];
  int r0 = (e0 >= 0) ? atomicAdd(&lc[e0], 1) : -1;
  int r1 = (e1 >= 0) ? atomicAdd(&lc[e1], 1) : -1;
  __syncthreads();
  if (tid < NEXP) lbase[tid] = atomicAdd(&cursor[tid], lc[tid]);
  __syncthreads();
  int p0 = -1, p1 = -1;
  if (e0 >= 0) { p0 = lbase[e0] + r0; sel_tok[p0] = t; sel_w[p0] = 2.5f * tk_w[2 * t]; }
  if (e1 >= 0) { p1 = lbase[e1] + r1; sel_tok[p1] = t; sel_w[p1] = 2.5f * tk_w[2 * t + 1]; }
  pos[2 * t] = p0;
  pos[2 * t + 1] = p1;
}

// ======== GEMM1+SiLU: 128x256 block, 4x8 frags, BALANCED XCD-local mapping ========
// b -> (ti, y): y = b&3, ti = 2*(b>>3) + ((b>>2)&1).  Under round-robin dispatch
// (XCD = b%8), XCD k hosts ONLY y=k&3 (B-panel L2-local) and ti of parity k>>2,
// stride 2 -> active-tile prefix splits evenly across all 8 XCDs (fixes R4's
// imbalance while keeping R4's FETCH halving).
__global__ __launch_bounds__(256, 2) void gemm1_kernel(
    const bf16_t* __restrict__ xb, const bf16_t* __restrict__ w13b,
    const int* __restrict__ sel_tok, const int* __restrict__ tile_e,
    const int* __restrict__ tile_p0, const int* __restrict__ n_mtiles,
    bf16_t* __restrict__ actb) {
  const int b = blockIdx.x;                       // 544 blocks
  const int ti = 2 * (b >> 3) + ((b >> 2) & 1);
  const int g0 = (b & 3) * 128;                   // gate-col base
  if (ti >= *n_mtiles) return;
  const int e = tile_e[ti];
  const int p0 = tile_p0[ti];

  __shared__ alignas(16) bf16_t As[128 * 64];
  __shared__ alignas(16) bf16_t Bs[256 * 64];
  const int tid = threadIdx.x;
  const int w = tid >> 6, l = tid & 63;
  const int wr = w >> 1, wc = w & 1;
  const int quad = l >> 4, c16 = l & 15;

  const int srow = tid >> 3;
  const int csrc = ((tid & 7) ^ (srow & 7)) * 8;
  const bf16_t* w13e = w13b + (size_t)e * (2 * IDIM) * HDIM;
  const bf16_t* Asrc[4];
  const bf16_t* Bsrc[8];
#pragma unroll
  for (int s = 0; s < 4; s++) {
    int tok = sel_tok[p0 + s * 32 + srow];
    Asrc[s] = xb + (size_t)tok * HDIM + csrc;
  }
#pragma unroll
  for (int s = 0; s < 8; s++) {
    int col = g0 + (s >> 1) * 32 + srow + ((s & 1) ? IDIM : 0);
    Bsrc[s] = w13e + (size_t)col * HDIM + csrc;
  }

  f32x4 acc[4][8];
#pragma unroll
  for (int i = 0; i < 4; i++)
#pragma unroll
    for (int j = 0; j < 8; j++) acc[i][j] = (f32x4){0.f, 0.f, 0.f, 0.f};

  for (int k0 = 0; k0 < HDIM; k0 += 64) {
#pragma unroll
    for (int s = 0; s < 4; s++) gll16(Asrc[s] + k0, &As[s * 2048 + w * 512]);
#pragma unroll
    for (int s = 0; s < 8; s++) gll16(Bsrc[s] + k0, &Bs[s * 2048 + w * 512]);
    __syncthreads();
#pragma unroll
    for (int kk = 0; kk < 2; kk++) {
      const int kch = ((kk * 4 + quad) ^ (c16 & 7)) * 8;
      bf16x8 af[4], bfv[8];
#pragma unroll
      for (int mt = 0; mt < 4; mt++)
        af[mt] = *(const bf16x8*)&As[(wr * 64 + mt * 16 + c16) * 64 + kch];
#pragma unroll
      for (int nt = 0; nt < 8; nt++)
        bfv[nt] = *(const bf16x8*)&Bs[(wc * 128 + nt * 16 + c16) * 64 + kch];
#pragma unroll
      for (int mt = 0; mt < 4; mt++)
#pragma unroll
        for (int nt = 0; nt < 8; nt++)
          acc[mt][nt] = __builtin_amdgcn_mfma_f32_16x16x32_bf16(af[mt], bfv[nt], acc[mt][nt], 0, 0, 0);
    }
    __syncthreads();
  }

#pragma unroll
  for (int mt = 0; mt < 4; mt++) {
    int rowb = p0 + wr * 64 + mt * 16 + quad * 4;
#pragma unroll
    for (int ntg = 0; ntg < 4; ntg++) {
      int nt = (ntg & 1) + (ntg >> 1) * 4;           // 0,1,4,5 = gate; nt+2 = up
      int col = g0 + (wc * 2 + (nt >> 2)) * 32 + (nt & 1) * 16 + c16;
#pragma unroll
      for (int r = 0; r < 4; r++) {
        float g = acc[mt][nt][r];
        float u = acc[mt][nt + 2][r];
        float s = g / (1.f + expf(-g));
        actb[(size_t)(rowb + r) * IDIM + col] = (bf16_t)(s * u);
      }
    }
  }
}

// ======== GEMM2: 128x256 block, 4x8 frags, balanced XCD-local mapping ========
__global__ __launch_bounds__(256, 2) void gemm2_kernel(
    const bf16_t* __restrict__ actb, const bf16_t* __restrict__ w2b,
    const float* __restrict__ sel_w, const int* __restrict__ tile_e,
    const int* __restrict__ tile_p0, const int* __restrict__ n_mtiles,
    bf16_t* __restrict__ eob) {
  const int b = blockIdx.x;                       // 544 blocks
  const int ti = 2 * (b >> 3) + ((b >> 2) & 1);
  const int n0 = (b & 3) * 256;
  if (ti >= *n_mtiles) return;
  const int e = tile_e[ti];
  const int p0 = tile_p0[ti];

  __shared__ alignas(16) bf16_t As[128 * 64];
  __shared__ alignas(16) bf16_t Bs[256 * 64];
  const int tid = threadIdx.x;
  const int w = tid >> 6, l = tid & 63;
  const int wr = w >> 1, wc = w & 1;
  const int quad = l >> 4, c16 = l & 15;

  const int srow = tid >> 3;
  const int csrc = ((tid & 7) ^ (srow & 7)) * 8;
  const bf16_t* w2e = w2b + (size_t)e * HDIM * IDIM;
  const bf16_t* Asrc[4];
  const bf16_t* Bsrc[8];
#pragma unroll
  for (int s = 0; s < 4; s++)
    Asrc[s] = actb + (size_t)(p0 + s * 32 + srow) * IDIM + csrc;
#pragma unroll
  for (int s = 0; s < 8; s++)
    Bsrc[s] = w2e + (size_t)(n0 + s * 32 + srow) * IDIM + csrc;

  f32x4 acc[4][8];
#pragma unroll
  for (int i = 0; i < 4; i++)
#pragma unroll
    for (int j = 0; j < 8; j++) acc[i][j] = (f32x4){0.f, 0.f, 0.f, 0.f};

  for (int k0 = 0; k0 < IDIM; k0 += 64) {
#pragma unroll
    for (int s = 0; s < 4; s++) gll16(Asrc[s] + k0, &As[s * 2048 + w * 512]);
#pragma unroll
    for (int s = 0; s < 8; s++) gll16(Bsrc[s] + k0, &Bs[s * 2048 + w * 512]);
    __syncthreads();
#pragma unroll
    for (int kk = 0; kk < 2; kk++) {
      const int kch = ((kk * 4 + quad) ^ (c16 & 7)) * 8;
      bf16x8 af[4], bfv[8];
#pragma unroll
      for (int mt = 0; mt < 4; mt++)
        af[mt] = *(const bf16x8*)&As[(wr * 64 + mt * 16 + c16) * 64 + kch];
#pragma unroll
      for (int nt = 0; nt < 8; nt++)
        bfv[nt] = *(const bf16x8*)&Bs[(wc * 128 + nt * 16 + c16) * 64 + kch];
#pragma unroll
      for (int mt = 0; mt < 4; mt++)
#pragma unroll
        for (int nt = 0; nt < 8; nt++)
          acc[mt][nt] = __builtin_amdgcn_mfma_f32_16x16x32_bf16(af[mt], bfv[nt], acc[mt][nt], 0, 0, 0);
    }
    __syncthreads();
  }

#pragma unroll
  for (int mt = 0; mt < 4; mt++) {
    int rowb = wr * 64 + mt * 16 + quad * 4;
    float cw[4];
#pragma unroll
    for (int r = 0; r < 4; r++) cw[r] = sel_w[p0 + rowb + r];
#pragma unroll
    for (int nt = 0; nt < 8; nt++) {
      int col = n0 + wc * 128 + nt * 16 + c16;
#pragma unroll
      for (int r = 0; r < 4; r++)
        eob[(size_t)(p0 + rowb + r) * HDIM + col] = (bf16_t)(cw[r] * acc[mt][nt][r]);
    }
  }
}

// ---------------- final combine ----------------
__global__ void combine_kernel(const float* __restrict__ x, const float* __restrict__ zscale,
                               const int* __restrict__ pos, const bf16_t* __restrict__ eob,
                               float* __restrict__ out) {
  size_t gid = (size_t)blockIdx.x * blockDim.x + threadIdx.x;
  size_t t = gid >> 7;
  size_t j = (gid & 127) << 3;
  float zs = zscale[t];
  int p0 = pos[2 * t], p1 = pos[2 * t + 1];
  float4 a = *(const float4*)&x[t * HDIM + j];
  float4 b = *(const float4*)&x[t * HDIM + j + 4];
  float o[8] = { zs * a.x, zs * a.y, zs * a.z, zs * a.w,
                 zs * b.x, zs * b.y, zs * b.z, zs * b.w };
  if (p0 >= 0) {
    bf16x8 v = *(const bf16x8*)&eob[(size_t)p0 * HDIM + j];
#pragma unroll
    for (int k = 0; k < 8; k++) o[k] += (float)v[k];
  }
  if (p1 >= 0) {
    bf16x8 v = *(const bf16x8*)&eob[(size_t)p1 * HDIM + j];
#pragma unroll
    for (int k = 0; k < 8; k++) o[k] += (float)v[k];
  }
  *(float4*)&out[t * HDIM + j] = make_float4(o[0], o[1], o[2], o[3]);
  *(float4*)&out[t * HDIM + j + 4] = make_float4(o[4], o[5], o[6], o[7]);
}

extern "C" void kernel_launch(void* const* d_in, const int* in_sizes, int n_in,
                              void* d_out, int out_size, void* d_ws, size_t ws_size,
                              hipStream_t stream) {
  const float* x    = (const float*)d_in[0];
  const float* rw   = (const float*)d_in[1];
  const float* bias = (const float*)d_in[2];
  const float* w13  = (const float*)d_in[3];
  const float* w2   = (const float*)d_in[4];
  float* out = (float*)d_out;

  char* ws = (char*)d_ws;
  bf16_t* w13b = (bf16_t*)ws;  ws += (size_t)NEXP * 2 * IDIM * HDIM * 2;
  bf16_t* w2b  = (bf16_t*)ws;  ws += (size_t)NEXP * HDIM * IDIM * 2;
  bf16_t* xb   = (bf16_t*)ws;  ws += (size_t)T_TOK * HDIM * 2;
  bf16_t* actb = (bf16_t*)ws;  ws += (size_t)MAXROWS * IDIM * 2;
  bf16_t* eob  = (bf16_t*)ws;  ws += (size_t)MAXROWS * HDIM * 2;
  int*   tk_e    = (int*)ws;   ws += (size_t)T_TOK * 2 * 4;
  float* tk_w    = (float*)ws; ws += (size_t)T_TOK * 2 * 4;
  float* zscale  = (float*)ws; ws += (size_t)T_TOK * 4;
  int*   pos     = (int*)ws;   ws += (size_t)T_TOK * 2 * 4;
  int*   sel_tok = (int*)ws;   ws += (size_t)MAXROWS * 4;
  float* sel_w   = (float*)ws; ws += (size_t)MAXROWS * 4;
  int*   cursor  = (int*)ws;   ws += NEXP * 4;
  int*   total_rows = (int*)ws; ws += 4;
  int*   tile_e  = (int*)ws;   ws += MAX_MTILES * 4;
  int*   tile_p0 = (int*)ws;   ws += MAX_MTILES * 4;
  int*   n_mtiles = (int*)ws;  ws += 4;

  // merged: weight casts + zero-init + router (+x->bf16)
  pre_kernel<<<WCAST_BLOCKS + T_TOK / 4, 256, 0, stream>>>(
      w13, w2, x, rw, bias, w13b, w2b, xb, tk_e, tk_w, zscale, sel_tok, sel_w);
  countscan_kernel<<<1, 256, 0, stream>>>(tk_e, cursor, total_rows,
                                          tile_e, tile_p0, n_mtiles);
  assign_kernel<<<T_TOK / 256, 256, 0, stream>>>(tk_e, tk_w, cursor, sel_tok, sel_w, pos);

  // GEMM1 + SiLU: balanced XCD-local 1-D grid (544)
  gemm1_kernel<<<MAX_MTILES * ((2 * IDIM) / 256), 256, 0, stream>>>(
      xb, w13b, sel_tok, tile_e, tile_p0, n_mtiles, actb);
  // GEMM2: balanced XCD-local 1-D grid (544)
  gemm2_kernel<<<MAX_MTILES * (HDIM / 256), 256, 0, stream>>>(
      actb, w2b, sel_w, tile_e, tile_p0, n_mtiles, eob);

  combine_kernel<<<(size_t)T_TOK * HDIM / 8 / 256, 256, 0, stream>>>(
      x, zscale, pos, eob, out);
}

// Round 6
// 231.453 us; speedup vs baseline: 1.1689x; 1.0198x over previous
//
#include <hip/hip_runtime.h>
#include <hip/hip_bf16.h>
#include <math.h>

typedef __bf16 bf16_t;
typedef bf16_t bf16x4 __attribute__((ext_vector_type(4)));
typedef bf16_t bf16x8 __attribute__((ext_vector_type(8)));
typedef float f32x4 __attribute__((ext_vector_type(4)));

#define T_TOK 8192
#define HDIM  1024
#define IDIM  512
#define NEXP  8
#define NTOT  12
#define MAXROWS (2 * T_TOK + NEXP * 128)   // 17408
#define MAX_MTILES (MAXROWS / 128)         // 136
#define WCAST_BLOCKS 6144                  // (n13+n2)/256 exactly
#define R_BLOCKS 512                       // router blocks, 16 tokens each

// ---------------- async global->LDS, 16B per lane ----------------
__device__ __forceinline__ void gll16(const bf16_t* g, bf16_t* l) {
  __builtin_amdgcn_global_load_lds((__attribute__((address_space(1))) void*)g,
                                   (__attribute__((address_space(3))) void*)l,
                                   16, 0, 0);
}

// ======== merged: weight casts + sel zero-init + router (+x->bf16 cast) ========
// Router role stages rw (48 KB fp32) in LDS once per block, amortized over 16
// tokens -> kills the 393 MB of per-wave global rw re-reads that throttled R5.
__global__ __launch_bounds__(256) void pre_kernel(
    const float* __restrict__ w13, const float* __restrict__ w2,
    const float* __restrict__ x, const float* __restrict__ rw,
    const float* __restrict__ bias,
    bf16_t* __restrict__ w13b, bf16_t* __restrict__ w2b, bf16_t* __restrict__ xb,
    int* __restrict__ tk_e, float* __restrict__ tk_w, float* __restrict__ zscale,
    int* __restrict__ sel_tok, float* __restrict__ sel_w) {
  __shared__ float rws[NTOT * HDIM];   // 48 KB
  const int bid = blockIdx.x;
  const int tid = threadIdx.x;
  if (bid < WCAST_BLOCKS) {
    size_t gid = (size_t)bid * 256 + tid;
    if (gid < MAXROWS) { sel_tok[gid] = 0; sel_w[gid] = 0.f; }
    const size_t n13 = (size_t)NEXP * 2 * IDIM * HDIM / 8;  // 1048576
    const float* in; bf16_t* outp; size_t i;
    if (gid < n13) { in = w13; outp = w13b; i = gid * 8; }
    else           { in = w2;  outp = w2b;  i = (gid - n13) * 8; }
    float4 a = *(const float4*)&in[i];
    float4 b = *(const float4*)&in[i + 4];
    bf16x8 o;
    o[0] = (bf16_t)a.x; o[1] = (bf16_t)a.y; o[2] = (bf16_t)a.z; o[3] = (bf16_t)a.w;
    o[4] = (bf16_t)b.x; o[5] = (bf16_t)b.y; o[6] = (bf16_t)b.z; o[7] = (bf16_t)b.w;
    *(bf16x8*)&outp[i] = o;
    return;
  }
  // ---- router role: stage rw to LDS, then 4 waves x 4 tokens ----
#pragma unroll
  for (int i = 0; i < NTOT * HDIM / 4 / 256; i++)
    ((float4*)rws)[i * 256 + tid] = ((const float4*)rw)[i * 256 + tid];
  __syncthreads();
  const int wv = tid >> 6, l = tid & 63;
  const int tbase = (bid - WCAST_BLOCKS) * 16 + wv * 4;
  for (int k = 0; k < 4; k++) {
    int t = tbase + k;
    const float4* xr = (const float4*)(x + (size_t)t * HDIM);
    float4 xv[4];
#pragma unroll
    for (int i = 0; i < 4; i++) xv[i] = xr[l + 64 * i];
#pragma unroll
    for (int i = 0; i < 4; i++) {
      bf16x4 o;
      o[0] = (bf16_t)xv[i].x; o[1] = (bf16_t)xv[i].y;
      o[2] = (bf16_t)xv[i].z; o[3] = (bf16_t)xv[i].w;
      *(bf16x4*)&xb[(size_t)t * HDIM + (size_t)(l + 64 * i) * 4] = o;
    }
    float part[NTOT];
#pragma unroll
    for (int e = 0; e < NTOT; e++) {
      const float4* wr = (const float4*)(rws + e * HDIM);
      float s = 0.f;
#pragma unroll
      for (int i = 0; i < 4; i++) {
        float4 w = wr[l + 64 * i];
        s += xv[i].x * w.x + xv[i].y * w.y + xv[i].z * w.z + xv[i].w * w.w;
      }
      part[e] = s;
    }
#pragma unroll
    for (int off = 32; off > 0; off >>= 1)
#pragma unroll
      for (int e = 0; e < NTOT; e++) part[e] += __shfl_down(part[e], off);

    if (l == 0) {
      float mx = part[0];
#pragma unroll
      for (int e = 1; e < NTOT; e++) mx = fmaxf(mx, part[e]);
      float p[NTOT], den = 0.f;
#pragma unroll
      for (int e = 0; e < NTOT; e++) { p[e] = expf(part[e] - mx); den += p[e]; }
      float inv = 1.f / den;
#pragma unroll
      for (int e = 0; e < NTOT; e++) p[e] *= inv;
      float s0 = -1e30f, s1 = -1e30f; int i0 = 0, i1 = 0;
#pragma unroll
      for (int e = 0; e < NTOT; e++) {
        float v = p[e] + bias[e];
        if (v > s0) { s1 = s0; i1 = i0; s0 = v; i0 = e; }
        else if (v > s1) { s1 = v; i1 = e; }
      }
      float zs = 0.f;
      int idx[2] = { i0, i1 };
#pragma unroll
      for (int kk = 0; kk < 2; kk++) {
        int e = idx[kk];
        float w = p[e];
        if (e >= NEXP) { zs += w; tk_e[2 * t + kk] = -1; tk_w[2 * t + kk] = 0.f; }
        else           { tk_e[2 * t + kk] = e; tk_w[2 * t + kk] = w; }
      }
      zscale[t] = zs;
    }
  }
}

// ---------------- fused count + scan (single block) ----------------
__global__ void countscan_kernel(const int* __restrict__ tk_e, int* __restrict__ cursor,
                                 int* __restrict__ total_rows, int* __restrict__ tile_e,
                                 int* __restrict__ tile_p0, int* __restrict__ n_mtiles) {
  __shared__ int lc[NEXP];
  int tid = threadIdx.x;
  if (tid < NEXP) lc[tid] = 0;
  __syncthreads();
  int cnt[NEXP];
#pragma unroll
  for (int j = 0; j < NEXP; j++) cnt[j] = 0;
  for (int i = tid; i < 2 * T_TOK; i += 256) {
    int e = tk_e[i];
#pragma unroll
    for (int j = 0; j < NEXP; j++) cnt[j] += (e == j) ? 1 : 0;
  }
#pragma unroll
  for (int off = 32; off > 0; off >>= 1)
#pragma unroll
    for (int j = 0; j < NEXP; j++) cnt[j] += __shfl_down(cnt[j], off);
  if ((tid & 63) == 0)
#pragma unroll
    for (int j = 0; j < NEXP; j++) atomicAdd(&lc[j], cnt[j]);
  __syncthreads();
  if (tid == 0) {
    int run = 0, nt = 0;
    for (int e = 0; e < NEXP; e++) {
      cursor[e] = run;
      int ntile = (lc[e] + 127) / 128;
      for (int i = 0; i < ntile; i++) {
        tile_e[nt] = e;
        tile_p0[nt] = run + i * 128;
        nt++;
      }
      run += ntile * 128;
    }
    *total_rows = run;
    *n_mtiles = nt;
  }
}

// ---------------- assign (writes pos for combine) ----------------
__global__ void assign_kernel(const int* __restrict__ tk_e, const float* __restrict__ tk_w,
                              int* __restrict__ cursor, int* __restrict__ sel_tok,
                              float* __restrict__ sel_w, int* __restrict__ pos) {
  __shared__ int lc[NEXP];
  __shared__ int lbase[NEXP];
  int tid = threadIdx.x;
  if (tid < NEXP) lc[tid] = 0;
  __syncthreads();
  int t = blockIdx.x * blockDim.x + tid;
  int e0 = tk_e[2 * t], e1 = tk_e[2 * t + 1];
  int r0 = (e0 >= 0) ? atomicAdd(&lc[e0], 1) : -1;
  int r1 = (e1 >= 0) ? atomicAdd(&lc[e1], 1) : -1;
  __syncthreads();
  if (tid < NEXP) lbase[tid] = atomicAdd(&cursor[tid], lc[tid]);
  __syncthreads();
  int p0 = -1, p1 = -1;
  if (e0 >= 0) { p0 = lbase[e0] + r0; sel_tok[p0] = t; sel_w[p0] = 2.5f * tk_w[2 * t]; }
  if (e1 >= 0) { p1 = lbase[e1] + r1; sel_tok[p1] = t; sel_w[p1] = 2.5f * tk_w[2 * t + 1]; }
  pos[2 * t] = p0;
  pos[2 * t + 1] = p1;
}

// ======== GEMM1+SiLU: 128x256 block, 4x8 frags, BALANCED XCD-local mapping ========
// b -> (ti, y): y = b&3, ti = 2*(b>>3) + ((b>>2)&1).  XCD k (b%8) hosts only
// y=k&3 (B-panel L2-local) and ti of parity k>>2, stride 2 -> even split of the
// active-tile prefix across XCDs.
__global__ __launch_bounds__(256, 2) void gemm1_kernel(
    const bf16_t* __restrict__ xb, const bf16_t* __restrict__ w13b,
    const int* __restrict__ sel_tok, const int* __restrict__ tile_e,
    const int* __restrict__ tile_p0, const int* __restrict__ n_mtiles,
    bf16_t* __restrict__ actb) {
  const int b = blockIdx.x;                       // 544 blocks
  const int ti = 2 * (b >> 3) + ((b >> 2) & 1);
  const int g0 = (b & 3) * 128;                   // gate-col base
  if (ti >= *n_mtiles) return;
  const int e = tile_e[ti];
  const int p0 = tile_p0[ti];

  __shared__ alignas(16) bf16_t As[128 * 64];
  __shared__ alignas(16) bf16_t Bs[256 * 64];
  const int tid = threadIdx.x;
  const int w = tid >> 6, l = tid & 63;
  const int wr = w >> 1, wc = w & 1;
  const int quad = l >> 4, c16 = l & 15;

  const int srow = tid >> 3;
  const int csrc = ((tid & 7) ^ (srow & 7)) * 8;
  const bf16_t* w13e = w13b + (size_t)e * (2 * IDIM) * HDIM;
  const bf16_t* Asrc[4];
  const bf16_t* Bsrc[8];
#pragma unroll
  for (int s = 0; s < 4; s++) {
    int tok = sel_tok[p0 + s * 32 + srow];
    Asrc[s] = xb + (size_t)tok * HDIM + csrc;
  }
#pragma unroll
  for (int s = 0; s < 8; s++) {
    int col = g0 + (s >> 1) * 32 + srow + ((s & 1) ? IDIM : 0);
    Bsrc[s] = w13e + (size_t)col * HDIM + csrc;
  }

  f32x4 acc[4][8];
#pragma unroll
  for (int i = 0; i < 4; i++)
#pragma unroll
    for (int j = 0; j < 8; j++) acc[i][j] = (f32x4){0.f, 0.f, 0.f, 0.f};

  for (int k0 = 0; k0 < HDIM; k0 += 64) {
#pragma unroll
    for (int s = 0; s < 4; s++) gll16(Asrc[s] + k0, &As[s * 2048 + w * 512]);
#pragma unroll
    for (int s = 0; s < 8; s++) gll16(Bsrc[s] + k0, &Bs[s * 2048 + w * 512]);
    __syncthreads();
#pragma unroll
    for (int kk = 0; kk < 2; kk++) {
      const int kch = ((kk * 4 + quad) ^ (c16 & 7)) * 8;
      bf16x8 af[4], bfv[8];
#pragma unroll
      for (int mt = 0; mt < 4; mt++)
        af[mt] = *(const bf16x8*)&As[(wr * 64 + mt * 16 + c16) * 64 + kch];
#pragma unroll
      for (int nt = 0; nt < 8; nt++)
        bfv[nt] = *(const bf16x8*)&Bs[(wc * 128 + nt * 16 + c16) * 64 + kch];
#pragma unroll
      for (int mt = 0; mt < 4; mt++)
#pragma unroll
        for (int nt = 0; nt < 8; nt++)
          acc[mt][nt] = __builtin_amdgcn_mfma_f32_16x16x32_bf16(af[mt], bfv[nt], acc[mt][nt], 0, 0, 0);
    }
    __syncthreads();
  }

#pragma unroll
  for (int mt = 0; mt < 4; mt++) {
    int rowb = p0 + wr * 64 + mt * 16 + quad * 4;
#pragma unroll
    for (int ntg = 0; ntg < 4; ntg++) {
      int nt = (ntg & 1) + (ntg >> 1) * 4;           // 0,1,4,5 = gate; nt+2 = up
      int col = g0 + (wc * 2 + (nt >> 2)) * 32 + (nt & 1) * 16 + c16;
#pragma unroll
      for (int r = 0; r < 4; r++) {
        float g = acc[mt][nt][r];
        float u = acc[mt][nt + 2][r];
        float s = g / (1.f + expf(-g));
        actb[(size_t)(rowb + r) * IDIM + col] = (bf16_t)(s * u);
      }
    }
  }
}

// ======== GEMM2: 128x256 block, 4x8 frags, balanced XCD-local mapping ========
__global__ __launch_bounds__(256, 2) void gemm2_kernel(
    const bf16_t* __restrict__ actb, const bf16_t* __restrict__ w2b,
    const float* __restrict__ sel_w, const int* __restrict__ tile_e,
    const int* __restrict__ tile_p0, const int* __restrict__ n_mtiles,
    bf16_t* __restrict__ eob) {
  const int b = blockIdx.x;                       // 544 blocks
  const int ti = 2 * (b >> 3) + ((b >> 2) & 1);
  const int n0 = (b & 3) * 256;
  if (ti >= *n_mtiles) return;
  const int e = tile_e[ti];
  const int p0 = tile_p0[ti];

  __shared__ alignas(16) bf16_t As[128 * 64];
  __shared__ alignas(16) bf16_t Bs[256 * 64];
  const int tid = threadIdx.x;
  const int w = tid >> 6, l = tid & 63;
  const int wr = w >> 1, wc = w & 1;
  const int quad = l >> 4, c16 = l & 15;

  const int srow = tid >> 3;
  const int csrc = ((tid & 7) ^ (srow & 7)) * 8;
  const bf16_t* w2e = w2b + (size_t)e * HDIM * IDIM;
  const bf16_t* Asrc[4];
  const bf16_t* Bsrc[8];
#pragma unroll
  for (int s = 0; s < 4; s++)
    Asrc[s] = actb + (size_t)(p0 + s * 32 + srow) * IDIM + csrc;
#pragma unroll
  for (int s = 0; s < 8; s++)
    Bsrc[s] = w2e + (size_t)(n0 + s * 32 + srow) * IDIM + csrc;

  f32x4 acc[4][8];
#pragma unroll
  for (int i = 0; i < 4; i++)
#pragma unroll
    for (int j = 0; j < 8; j++) acc[i][j] = (f32x4){0.f, 0.f, 0.f, 0.f};

  for (int k0 = 0; k0 < IDIM; k0 += 64) {
#pragma unroll
    for (int s = 0; s < 4; s++) gll16(Asrc[s] + k0, &As[s * 2048 + w * 512]);
#pragma unroll
    for (int s = 0; s < 8; s++) gll16(Bsrc[s] + k0, &Bs[s * 2048 + w * 512]);
    __syncthreads();
#pragma unroll
    for (int kk = 0; kk < 2; kk++) {
      const int kch = ((kk * 4 + quad) ^ (c16 & 7)) * 8;
      bf16x8 af[4], bfv[8];
#pragma unroll
      for (int mt = 0; mt < 4; mt++)
        af[mt] = *(const bf16x8*)&As[(wr * 64 + mt * 16 + c16) * 64 + kch];
#pragma unroll
      for (int nt = 0; nt < 8; nt++)
        bfv[nt] = *(const bf16x8*)&Bs[(wc * 128 + nt * 16 + c16) * 64 + kch];
#pragma unroll
      for (int mt = 0; mt < 4; mt++)
#pragma unroll
        for (int nt = 0; nt < 8; nt++)
          acc[mt][nt] = __builtin_amdgcn_mfma_f32_16x16x32_bf16(af[mt], bfv[nt], acc[mt][nt], 0, 0, 0);
    }
    __syncthreads();
  }

#pragma unroll
  for (int mt = 0; mt < 4; mt++) {
    int rowb = wr * 64 + mt * 16 + quad * 4;
    float cw[4];
#pragma unroll
    for (int r = 0; r < 4; r++) cw[r] = sel_w[p0 + rowb + r];
#pragma unroll
    for (int nt = 0; nt < 8; nt++) {
      int col = n0 + wc * 128 + nt * 16 + c16;
#pragma unroll
      for (int r = 0; r < 4; r++)
        eob[(size_t)(p0 + rowb + r) * HDIM + col] = (bf16_t)(cw[r] * acc[mt][nt][r]);
    }
  }
}

// ---------------- final combine ----------------
__global__ void combine_kernel(const float* __restrict__ x, const float* __restrict__ zscale,
                               const int* __restrict__ pos, const bf16_t* __restrict__ eob,
                               float* __restrict__ out) {
  size_t gid = (size_t)blockIdx.x * blockDim.x + threadIdx.x;
  size_t t = gid >> 7;
  size_t j = (gid & 127) << 3;
  float zs = zscale[t];
  int p0 = pos[2 * t], p1 = pos[2 * t + 1];
  float4 a = *(const float4*)&x[t * HDIM + j];
  float4 b = *(const float4*)&x[t * HDIM + j + 4];
  float o[8] = { zs * a.x, zs * a.y, zs * a.z, zs * a.w,
                 zs * b.x, zs * b.y, zs * b.z, zs * b.w };
  if (p0 >= 0) {
    bf16x8 v = *(const bf16x8*)&eob[(size_t)p0 * HDIM + j];
#pragma unroll
    for (int k = 0; k < 8; k++) o[k] += (float)v[k];
  }
  if (p1 >= 0) {
    bf16x8 v = *(const bf16x8*)&eob[(size_t)p1 * HDIM + j];
#pragma unroll
    for (int k = 0; k < 8; k++) o[k] += (float)v[k];
  }
  *(float4*)&out[t * HDIM + j] = make_float4(o[0], o[1], o[2], o[3]);
  *(float4*)&out[t * HDIM + j + 4] = make_float4(o[4], o[5], o[6], o[7]);
}

extern "C" void kernel_launch(void* const* d_in, const int* in_sizes, int n_in,
                              void* d_out, int out_size, void* d_ws, size_t ws_size,
                              hipStream_t stream) {
  const float* x    = (const float*)d_in[0];
  const float* rw   = (const float*)d_in[1];
  const float* bias = (const float*)d_in[2];
  const float* w13  = (const float*)d_in[3];
  const float* w2   = (const float*)d_in[4];
  float* out = (float*)d_out;

  char* ws = (char*)d_ws;
  bf16_t* w13b = (bf16_t*)ws;  ws += (size_t)NEXP * 2 * IDIM * HDIM * 2;
  bf16_t* w2b  = (bf16_t*)ws;  ws += (size_t)NEXP * HDIM * IDIM * 2;
  bf16_t* xb   = (bf16_t*)ws;  ws += (size_t)T_TOK * HDIM * 2;
  bf16_t* actb = (bf16_t*)ws;  ws += (size_t)MAXROWS * IDIM * 2;
  bf16_t* eob  = (bf16_t*)ws;  ws += (size_t)MAXROWS * HDIM * 2;
  int*   tk_e    = (int*)ws;   ws += (size_t)T_TOK * 2 * 4;
  float* tk_w    = (float*)ws; ws += (size_t)T_TOK * 2 * 4;
  float* zscale  = (float*)ws; ws += (size_t)T_TOK * 4;
  int*   pos     = (int*)ws;   ws += (size_t)T_TOK * 2 * 4;
  int*   sel_tok = (int*)ws;   ws += (size_t)MAXROWS * 4;
  float* sel_w   = (float*)ws; ws += (size_t)MAXROWS * 4;
  int*   cursor  = (int*)ws;   ws += NEXP * 4;
  int*   total_rows = (int*)ws; ws += 4;
  int*   tile_e  = (int*)ws;   ws += MAX_MTILES * 4;
  int*   tile_p0 = (int*)ws;   ws += MAX_MTILES * 4;
  int*   n_mtiles = (int*)ws;  ws += 4;

  // merged: weight casts + zero-init + router (rw LDS-staged, 16 tok/block)
  pre_kernel<<<WCAST_BLOCKS + R_BLOCKS, 256, 0, stream>>>(
      w13, w2, x, rw, bias, w13b, w2b, xb, tk_e, tk_w, zscale, sel_tok, sel_w);
  countscan_kernel<<<1, 256, 0, stream>>>(tk_e, cursor, total_rows,
                                          tile_e, tile_p0, n_mtiles);
  assign_kernel<<<T_TOK / 256, 256, 0, stream>>>(tk_e, tk_w, cursor, sel_tok, sel_w, pos);

  // GEMM1 + SiLU: balanced XCD-local 1-D grid (544)
  gemm1_kernel<<<MAX_MTILES * ((2 * IDIM) / 256), 256, 0, stream>>>(
      xb, w13b, sel_tok, tile_e, tile_p0, n_mtiles, actb);
  // GEMM2: balanced XCD-local 1-D grid (544)
  gemm2_kernel<<<MAX_MTILES * (HDIM / 256), 256, 0, stream>>>(
      actb, w2b, sel_w, tile_e, tile_p0, n_mtiles, eob);

  combine_kernel<<<(size_t)T_TOK * HDIM / 8 / 256, 256, 0, stream>>>(
      x, zscale, pos, eob, out);
}

// Round 8
// 230.763 us; speedup vs baseline: 1.1724x; 1.0030x over previous
//
#include <hip/hip_runtime.h>
#include <hip/hip_bf16.h>
#include <math.h>

typedef __bf16 bf16_t;
typedef bf16_t bf16x4 __attribute__((ext_vector_type(4)));
typedef bf16_t bf16x8 __attribute__((ext_vector_type(8)));
typedef float f32x4 __attribute__((ext_vector_type(4)));

#define T_TOK 8192
#define HDIM  1024
#define IDIM  512
#define NEXP  8
#define NTOT  12
#define MAXROWS (2 * T_TOK + NEXP * 128)   // 17408
#define MAX_MTILES (MAXROWS / 128)         // 136
#define WCAST_BLOCKS 6144                  // (n13+n2)/256 exactly
#define R_BLOCKS 512                       // router blocks, 16 tokens each

// ---------------- async global->LDS, 16B per lane ----------------
__device__ __forceinline__ void gll16(const bf16_t* g, bf16_t* l) {
  __builtin_amdgcn_global_load_lds((__attribute__((address_space(1))) void*)g,
                                   (__attribute__((address_space(3))) void*)l,
                                   16, 0, 0);
}

// ======== wcast: weight fp32->bf16 + sel zero-init (NO LDS -> full occupancy) ========
// MUST run before assign_kernel (assign overwrites the zero-init for active rows).
__global__ __launch_bounds__(256) void wcast_kernel(
    const float* __restrict__ w13, const float* __restrict__ w2,
    bf16_t* __restrict__ w13b, bf16_t* __restrict__ w2b,
    int* __restrict__ sel_tok, float* __restrict__ sel_w) {
  size_t gid = (size_t)blockIdx.x * blockDim.x + threadIdx.x;
  if (gid < MAXROWS) { sel_tok[gid] = 0; sel_w[gid] = 0.f; }
  const size_t n13 = (size_t)NEXP * 2 * IDIM * HDIM / 8;  // 1048576
  const float* in; bf16_t* outp; size_t i;
  if (gid < n13) { in = w13; outp = w13b; i = gid * 8; }
  else           { in = w2;  outp = w2b;  i = (gid - n13) * 8; }
  float4 a = *(const float4*)&in[i];
  float4 b = *(const float4*)&in[i + 4];
  bf16x8 o;
  o[0] = (bf16_t)a.x; o[1] = (bf16_t)a.y; o[2] = (bf16_t)a.z; o[3] = (bf16_t)a.w;
  o[4] = (bf16_t)b.x; o[5] = (bf16_t)b.y; o[6] = (bf16_t)b.z; o[7] = (bf16_t)b.w;
  *(bf16x8*)&outp[i] = o;
}

// ======== router: rw LDS-staged once per block, 16 tokens/block (+x->bf16) ========
__global__ __launch_bounds__(256) void router_kernel(
    const float* __restrict__ x, const float* __restrict__ rw,
    const float* __restrict__ bias,
    bf16_t* __restrict__ xb,
    int* __restrict__ tk_e, float* __restrict__ tk_w, float* __restrict__ zscale) {
  __shared__ float rws[NTOT * HDIM];   // 48 KB
  const int bid = blockIdx.x;
  const int tid = threadIdx.x;
#pragma unroll
  for (int i = 0; i < NTOT * HDIM / 4 / 256; i++)
    ((float4*)rws)[i * 256 + tid] = ((const float4*)rw)[i * 256 + tid];
  __syncthreads();
  const int wv = tid >> 6, l = tid & 63;
  const int tbase = bid * 16 + wv * 4;
  for (int k = 0; k < 4; k++) {
    int t = tbase + k;
    const float4* xr = (const float4*)(x + (size_t)t * HDIM);
    float4 xv[4];
#pragma unroll
    for (int i = 0; i < 4; i++) xv[i] = xr[l + 64 * i];
#pragma unroll
    for (int i = 0; i < 4; i++) {
      bf16x4 o;
      o[0] = (bf16_t)xv[i].x; o[1] = (bf16_t)xv[i].y;
      o[2] = (bf16_t)xv[i].z; o[3] = (bf16_t)xv[i].w;
      *(bf16x4*)&xb[(size_t)t * HDIM + (size_t)(l + 64 * i) * 4] = o;
    }
    float part[NTOT];
#pragma unroll
    for (int e = 0; e < NTOT; e++) {
      const float4* wr = (const float4*)(rws + e * HDIM);
      float s = 0.f;
#pragma unroll
      for (int i = 0; i < 4; i++) {
        float4 w = wr[l + 64 * i];
        s += xv[i].x * w.x + xv[i].y * w.y + xv[i].z * w.z + xv[i].w * w.w;
      }
      part[e] = s;
    }
#pragma unroll
    for (int off = 32; off > 0; off >>= 1)
#pragma unroll
      for (int e = 0; e < NTOT; e++) part[e] += __shfl_down(part[e], off);

    if (l == 0) {
      float mx = part[0];
#pragma unroll
      for (int e = 1; e < NTOT; e++) mx = fmaxf(mx, part[e]);
      float p[NTOT], den = 0.f;
#pragma unroll
      for (int e = 0; e < NTOT; e++) { p[e] = expf(part[e] - mx); den += p[e]; }
      float inv = 1.f / den;
#pragma unroll
      for (int e = 0; e < NTOT; e++) p[e] *= inv;
      float s0 = -1e30f, s1 = -1e30f; int i0 = 0, i1 = 0;
#pragma unroll
      for (int e = 0; e < NTOT; e++) {
        float v = p[e] + bias[e];
        if (v > s0) { s1 = s0; i1 = i0; s0 = v; i0 = e; }
        else if (v > s1) { s1 = v; i1 = e; }
      }
      float zs = 0.f;
      int idx[2] = { i0, i1 };
#pragma unroll
      for (int kk = 0; kk < 2; kk++) {
        int e = idx[kk];
        float w = p[e];
        if (e >= NEXP) { zs += w; tk_e[2 * t + kk] = -1; tk_w[2 * t + kk] = 0.f; }
        else           { tk_e[2 * t + kk] = e; tk_w[2 * t + kk] = w; }
      }
      zscale[t] = zs;
    }
  }
}

// ---------------- fused count + scan (single block) ----------------
__global__ void countscan_kernel(const int* __restrict__ tk_e, int* __restrict__ cursor,
                                 int* __restrict__ total_rows, int* __restrict__ tile_e,
                                 int* __restrict__ tile_p0, int* __restrict__ n_mtiles) {
  __shared__ int lc[NEXP];
  int tid = threadIdx.x;
  if (tid < NEXP) lc[tid] = 0;
  __syncthreads();
  int cnt[NEXP];
#pragma unroll
  for (int j = 0; j < NEXP; j++) cnt[j] = 0;
  for (int i = tid; i < 2 * T_TOK; i += 256) {
    int e = tk_e[i];
#pragma unroll
    for (int j = 0; j < NEXP; j++) cnt[j] += (e == j) ? 1 : 0;
  }
#pragma unroll
  for (int off = 32; off > 0; off >>= 1)
#pragma unroll
    for (int j = 0; j < NEXP; j++) cnt[j] += __shfl_down(cnt[j], off);
  if ((tid & 63) == 0)
#pragma unroll
    for (int j = 0; j < NEXP; j++) atomicAdd(&lc[j], cnt[j]);
  __syncthreads();
  if (tid == 0) {
    int run = 0, nt = 0;
    for (int e = 0; e < NEXP; e++) {
      cursor[e] = run;
      int ntile = (lc[e] + 127) / 128;
      for (int i = 0; i < ntile; i++) {
        tile_e[nt] = e;
        tile_p0[nt] = run + i * 128;
        nt++;
      }
      run += ntile * 128;
    }
    *total_rows = run;
    *n_mtiles = nt;
  }
}

// ---------------- assign (writes pos for combine) ----------------
__global__ void assign_kernel(const int* __restrict__ tk_e, const float* __restrict__ tk_w,
                              int* __restrict__ cursor, int* __restrict__ sel_tok,
                              float* __restrict__ sel_w, int* __restrict__ pos) {
  __shared__ int lc[NEXP];
  __shared__ int lbase[NEXP];
  int tid = threadIdx.x;
  if (tid < NEXP) lc[tid] = 0;
  __syncthreads();
  int t = blockIdx.x * blockDim.x + tid;
  int e0 = tk_e[2 * t], e1 = tk_e[2 * t + 1];
  int r0 = (e0 >= 0) ? atomicAdd(&lc[e0], 1) : -1;
  int r1 = (e1 >= 0) ? atomicAdd(&lc[e1], 1) : -1;
  __syncthreads();
  if (tid < NEXP) lbase[tid] = atomicAdd(&cursor[tid], lc[tid]);
  __syncthreads();
  int p0 = -1, p1 = -1;
  if (e0 >= 0) { p0 = lbase[e0] + r0; sel_tok[p0] = t; sel_w[p0] = 2.5f * tk_w[2 * t]; }
  if (e1 >= 0) { p1 = lbase[e1] + r1; sel_tok[p1] = t; sel_w[p1] = 2.5f * tk_w[2 * t + 1]; }
  pos[2 * t] = p0;
  pos[2 * t + 1] = p1;
}

// ======== GEMM1+SiLU: 128x256 block, 4x8 frags, BALANCED XCD-local mapping ========
// b -> (ti, y): y = b&3, ti = 2*(b>>3) + ((b>>2)&1).  XCD k (b%8) hosts only
// y=k&3 (B-panel L2-local) and ti of parity k>>2, stride 2 -> even split of the
// active-tile prefix across XCDs.
__global__ __launch_bounds__(256, 2) void gemm1_kernel(
    const bf16_t* __restrict__ xb, const bf16_t* __restrict__ w13b,
    const int* __restrict__ sel_tok, const int* __restrict__ tile_e,
    const int* __restrict__ tile_p0, const int* __restrict__ n_mtiles,
    bf16_t* __restrict__ actb) {
  const int b = blockIdx.x;                       // 544 blocks
  const int ti = 2 * (b >> 3) + ((b >> 2) & 1);
  const int g0 = (b & 3) * 128;                   // gate-col base
  if (ti >= *n_mtiles) return;
  const int e = tile_e[ti];
  const int p0 = tile_p0[ti];

  __shared__ alignas(16) bf16_t As[128 * 64];
  __shared__ alignas(16) bf16_t Bs[256 * 64];
  const int tid = threadIdx.x;
  const int w = tid >> 6, l = tid & 63;
  const int wr = w >> 1, wc = w & 1;
  const int quad = l >> 4, c16 = l & 15;

  const int srow = tid >> 3;
  const int csrc = ((tid & 7) ^ (srow & 7)) * 8;
  const bf16_t* w13e = w13b + (size_t)e * (2 * IDIM) * HDIM;
  const bf16_t* Asrc[4];
  const bf16_t* Bsrc[8];
#pragma unroll
  for (int s = 0; s < 4; s++) {
    int tok = sel_tok[p0 + s * 32 + srow];
    Asrc[s] = xb + (size_t)tok * HDIM + csrc;
  }
#pragma unroll
  for (int s = 0; s < 8; s++) {
    int col = g0 + (s >> 1) * 32 + srow + ((s & 1) ? IDIM : 0);
    Bsrc[s] = w13e + (size_t)col * HDIM + csrc;
  }

  f32x4 acc[4][8];
#pragma unroll
  for (int i = 0; i < 4; i++)
#pragma unroll
    for (int j = 0; j < 8; j++) acc[i][j] = (f32x4){0.f, 0.f, 0.f, 0.f};

  for (int k0 = 0; k0 < HDIM; k0 += 64) {
#pragma unroll
    for (int s = 0; s < 4; s++) gll16(Asrc[s] + k0, &As[s * 2048 + w * 512]);
#pragma unroll
    for (int s = 0; s < 8; s++) gll16(Bsrc[s] + k0, &Bs[s * 2048 + w * 512]);
    __syncthreads();
#pragma unroll
    for (int kk = 0; kk < 2; kk++) {
      const int kch = ((kk * 4 + quad) ^ (c16 & 7)) * 8;
      bf16x8 af[4], bfv[8];
#pragma unroll
      for (int mt = 0; mt < 4; mt++)
        af[mt] = *(const bf16x8*)&As[(wr * 64 + mt * 16 + c16) * 64 + kch];
#pragma unroll
      for (int nt = 0; nt < 8; nt++)
        bfv[nt] = *(const bf16x8*)&Bs[(wc * 128 + nt * 16 + c16) * 64 + kch];
#pragma unroll
      for (int mt = 0; mt < 4; mt++)
#pragma unroll
        for (int nt = 0; nt < 8; nt++)
          acc[mt][nt] = __builtin_amdgcn_mfma_f32_16x16x32_bf16(af[mt], bfv[nt], acc[mt][nt], 0, 0, 0);
    }
    __syncthreads();
  }

#pragma unroll
  for (int mt = 0; mt < 4; mt++) {
    int rowb = p0 + wr * 64 + mt * 16 + quad * 4;
#pragma unroll
    for (int ntg = 0; ntg < 4; ntg++) {
      int nt = (ntg & 1) + (ntg >> 1) * 4;           // 0,1,4,5 = gate; nt+2 = up
      int col = g0 + (wc * 2 + (nt >> 2)) * 32 + (nt & 1) * 16 + c16;
#pragma unroll
      for (int r = 0; r < 4; r++) {
        float g = acc[mt][nt][r];
        float u = acc[mt][nt + 2][r];
        float s = g / (1.f + expf(-g));
        actb[(size_t)(rowb + r) * IDIM + col] = (bf16_t)(s * u);
      }
    }
  }
}

// ======== GEMM2: 128x256 block, 4x8 frags, balanced XCD-local mapping ========
__global__ __launch_bounds__(256, 2) void gemm2_kernel(
    const bf16_t* __restrict__ actb, const bf16_t* __restrict__ w2b,
    const float* __restrict__ sel_w, const int* __restrict__ tile_e,
    const int* __restrict__ tile_p0, const int* __restrict__ n_mtiles,
    bf16_t* __restrict__ eob) {
  const int b = blockIdx.x;                       // 544 blocks
  const int ti = 2 * (b >> 3) + ((b >> 2) & 1);
  const int n0 = (b & 3) * 256;
  if (ti >= *n_mtiles) return;
  const int e = tile_e[ti];
  const int p0 = tile_p0[ti];

  __shared__ alignas(16) bf16_t As[128 * 64];
  __shared__ alignas(16) bf16_t Bs[256 * 64];
  const int tid = threadIdx.x;
  const int w = tid >> 6, l = tid & 63;
  const int wr = w >> 1, wc = w & 1;
  const int quad = l >> 4, c16 = l & 15;

  const int srow = tid >> 3;
  const int csrc = ((tid & 7) ^ (srow & 7)) * 8;
  const bf16_t* w2e = w2b + (size_t)e * HDIM * IDIM;
  const bf16_t* Asrc[4];
  const bf16_t* Bsrc[8];
#pragma unroll
  for (int s = 0; s < 4; s++)
    Asrc[s] = actb + (size_t)(p0 + s * 32 + srow) * IDIM + csrc;
#pragma unroll
  for (int s = 0; s < 8; s++)
    Bsrc[s] = w2e + (size_t)(n0 + s * 32 + srow) * IDIM + csrc;

  f32x4 acc[4][8];
#pragma unroll
  for (int i = 0; i < 4; i++)
#pragma unroll
    for (int j = 0; j < 8; j++) acc[i][j] = (f32x4){0.f, 0.f, 0.f, 0.f};

  for (int k0 = 0; k0 < IDIM; k0 += 64) {
#pragma unroll
    for (int s = 0; s < 4; s++) gll16(Asrc[s] + k0, &As[s * 2048 + w * 512]);
#pragma unroll
    for (int s = 0; s < 8; s++) gll16(Bsrc[s] + k0, &Bs[s * 2048 + w * 512]);
    __syncthreads();
#pragma unroll
    for (int kk = 0; kk < 2; kk++) {
      const int kch = ((kk * 4 + quad) ^ (c16 & 7)) * 8;
      bf16x8 af[4], bfv[8];
#pragma unroll
      for (int mt = 0; mt < 4; mt++)
        af[mt] = *(const bf16x8*)&As[(wr * 64 + mt * 16 + c16) * 64 + kch];
#pragma unroll
      for (int nt = 0; nt < 8; nt++)
        bfv[nt] = *(const bf16x8*)&Bs[(wc * 128 + nt * 16 + c16) * 64 + kch];
#pragma unroll
      for (int mt = 0; mt < 4; mt++)
#pragma unroll
        for (int nt = 0; nt < 8; nt++)
          acc[mt][nt] = __builtin_amdgcn_mfma_f32_16x16x32_bf16(af[mt], bfv[nt], acc[mt][nt], 0, 0, 0);
    }
    __syncthreads();
  }

#pragma unroll
  for (int mt = 0; mt < 4; mt++) {
    int rowb = wr * 64 + mt * 16 + quad * 4;
    float cw[4];
#pragma unroll
    for (int r = 0; r < 4; r++) cw[r] = sel_w[p0 + rowb + r];
#pragma unroll
    for (int nt = 0; nt < 8; nt++) {
      int col = n0 + wc * 128 + nt * 16 + c16;
#pragma unroll
      for (int r = 0; r < 4; r++)
        eob[(size_t)(p0 + rowb + r) * HDIM + col] = (bf16_t)(cw[r] * acc[mt][nt][r]);
    }
  }
}

// ---------------- final combine ----------------
__global__ void combine_kernel(const float* __restrict__ x, const float* __restrict__ zscale,
                               const int* __restrict__ pos, const bf16_t* __restrict__ eob,
                               float* __restrict__ out) {
  size_t gid = (size_t)blockIdx.x * blockDim.x + threadIdx.x;
  size_t t = gid >> 7;
  size_t j = (gid & 127) << 3;
  float zs = zscale[t];
  int p0 = pos[2 * t], p1 = pos[2 * t + 1];
  float4 a = *(const float4*)&x[t * HDIM + j];
  float4 b = *(const float4*)&x[t * HDIM + j + 4];
  float o[8] = { zs * a.x, zs * a.y, zs * a.z, zs * a.w,
                 zs * b.x, zs * b.y, zs * b.z, zs * b.w };
  if (p0 >= 0) {
    bf16x8 v = *(const bf16x8*)&eob[(size_t)p0 * HDIM + j];
#pragma unroll
    for (int k = 0; k < 8; k++) o[k] += (float)v[k];
  }
  if (p1 >= 0) {
    bf16x8 v = *(const bf16x8*)&eob[(size_t)p1 * HDIM + j];
#pragma unroll
    for (int k = 0; k < 8; k++) o[k] += (float)v[k];
  }
  *(float4*)&out[t * HDIM + j] = make_float4(o[0], o[1], o[2], o[3]);
  *(float4*)&out[t * HDIM + j + 4] = make_float4(o[4], o[5], o[6], o[7]);
}

extern "C" void kernel_launch(void* const* d_in, const int* in_sizes, int n_in,
                              void* d_out, int out_size, void* d_ws, size_t ws_size,
                              hipStream_t stream) {
  const float* x    = (const float*)d_in[0];
  const float* rw   = (const float*)d_in[1];
  const float* bias = (const float*)d_in[2];
  const float* w13  = (const float*)d_in[3];
  const float* w2   = (const float*)d_in[4];
  float* out = (float*)d_out;

  char* ws = (char*)d_ws;
  bf16_t* w13b = (bf16_t*)ws;  ws += (size_t)NEXP * 2 * IDIM * HDIM * 2;
  bf16_t* w2b  = (bf16_t*)ws;  ws += (size_t)NEXP * HDIM * IDIM * 2;
  bf16_t* xb   = (bf16_t*)ws;  ws += (size_t)T_TOK * HDIM * 2;
  bf16_t* actb = (bf16_t*)ws;  ws += (size_t)MAXROWS * IDIM * 2;
  bf16_t* eob  = (bf16_t*)ws;  ws += (size_t)MAXROWS * HDIM * 2;
  int*   tk_e    = (int*)ws;   ws += (size_t)T_TOK * 2 * 4;
  float* tk_w    = (float*)ws; ws += (size_t)T_TOK * 2 * 4;
  float* zscale  = (float*)ws; ws += (size_t)T_TOK * 4;
  int*   pos     = (int*)ws;   ws += (size_t)T_TOK * 2 * 4;
  int*   sel_tok = (int*)ws;   ws += (size_t)MAXROWS * 4;
  float* sel_w   = (float*)ws; ws += (size_t)MAXROWS * 4;
  int*   cursor  = (int*)ws;   ws += NEXP * 4;
  int*   total_rows = (int*)ws; ws += 4;
  int*   tile_e  = (int*)ws;   ws += MAX_MTILES * 4;
  int*   tile_p0 = (int*)ws;   ws += MAX_MTILES * 4;
  int*   n_mtiles = (int*)ws;  ws += 4;

  // wcast FIRST (carries sel zero-init that assign depends on), full occupancy
  wcast_kernel<<<WCAST_BLOCKS, 256, 0, stream>>>(w13, w2, w13b, w2b, sel_tok, sel_w);
  // router (48 KB LDS only here)
  router_kernel<<<R_BLOCKS, 256, 0, stream>>>(x, rw, bias, xb, tk_e, tk_w, zscale);
  countscan_kernel<<<1, 256, 0, stream>>>(tk_e, cursor, total_rows,
                                          tile_e, tile_p0, n_mtiles);
  assign_kernel<<<T_TOK / 256, 256, 0, stream>>>(tk_e, tk_w, cursor, sel_tok, sel_w, pos);

  // GEMM1 + SiLU: balanced XCD-local 1-D grid (544)
  gemm1_kernel<<<MAX_MTILES * ((2 * IDIM) / 256), 256, 0, stream>>>(
      xb, w13b, sel_tok, tile_e, tile_p0, n_mtiles, actb);
  // GEMM2: balanced XCD-local 1-D grid (544)
  gemm2_kernel<<<MAX_MTILES * (HDIM / 256), 256, 0, stream>>>(
      actb, w2b, sel_w, tile_e, tile_p0, n_mtiles, eob);

  combine_kernel<<<(size_t)T_TOK * HDIM / 8 / 256, 256, 0, stream>>>(
      x, zscale, pos, eob, out);
}